// Round 10
// baseline (370.193 us; speedup 1.0000x reference)
//
#include <hip/hip_runtime.h>
#include <hip/hip_bf16.h>

#define N_SEND 12288
#define N_REC  49152
#define NEDGE  196608
#define RECV   16          // receivers per block; M = 32 rows = 1 row-tile
#define CHK    32          // edges per DMA chunk (32 KB SBUF)

typedef __attribute__((ext_vector_type(8)))  short short8;
typedef __attribute__((ext_vector_type(4)))  short shortx4;
typedef __attribute__((ext_vector_type(4)))  float floatx4;
typedef __attribute__((ext_vector_type(16))) float floatx16;
typedef __attribute__((ext_vector_type(4)))  unsigned int uintx4;

__device__ inline short f2bs(float f) {
    __hip_bfloat16 h = __float2bfloat16(f);
    return *reinterpret_cast<short*>(&h);
}
// jax.nn.gelu default approximate=True (tanh form)
__device__ inline float gelu_tanh(float x) {
    const float k0 = 0.7978845608028654f;
    float u = k0 * (x + 0.044715f * x * x * x);
    float e = __expf(2.0f * u);
    float t = 1.0f - 2.0f / (e + 1.0f);
    return 0.5f * x * (1.0f + t);
}

__device__ inline void gload_lds16(const short* g, short* l) {
    __builtin_amdgcn_global_load_lds(
        (const __attribute__((address_space(1))) unsigned int*)g,
        (__attribute__((address_space(3))) unsigned int*)l, 16, 0, 0);
}

// ---- prep: BT1[n][0:256]=Wl1lo^T, BT1[n][256:512]=(We2@Wl1hi)^T, WT2=Wl2^T, cvec=be2@Wl1hi
__global__ void prep_kernel(const float* __restrict__ We2, const float* __restrict__ be2,
                            const float* __restrict__ Wl1, const float* __restrict__ Wl2,
                            short* __restrict__ BT1, short* __restrict__ WT2,
                            float* __restrict__ cvec) {
    int i = blockIdx.x;
    int n = threadIdx.x;
    if (i < 256) {
        float acc = 0.f;
        for (int j = 0; j < 256; ++j)
            acc += We2[i * 256 + j] * Wl1[(256 + j) * 256 + n];
        BT1[n * 512 + i]       = f2bs(Wl1[i * 256 + n]);   // k<256: Wl1lo
        BT1[n * 512 + 256 + i] = f2bs(acc);                // k>=256: M = We2@Wl1hi
        WT2[n * 256 + i]       = f2bs(Wl2[i * 256 + n]);
    } else {
        float acc = 0.f;
        for (int j = 0; j < 256; ++j)
            acc += be2[j] * Wl1[(256 + j) * 256 + n];
        cvec[n] = acc;
    }
}

// ---- xcast: Xb = bf16(X), interleaved [send][batch][256] (edge's 1KB contiguous)
__global__ void xcast_kernel(const float* __restrict__ X, short* __restrict__ Xb) {
    int i = (blockIdx.x * 256 + threadIdx.x) * 8;
    int row = i >> 8;                 // b*N_SEND + n
    int c   = i & 255;
    int bb_ = (row >= N_SEND) ? 1 : 0;
    int n   = row - bb_ * N_SEND;
    floatx4 v0 = *(const floatx4*)(X + i);
    floatx4 v1 = *(const floatx4*)(X + i + 4);
    short8 p;
#pragma unroll
    for (int j = 0; j < 4; ++j) { p[j] = f2bs(v0[j]); p[j + 4] = f2bs(v1[j]); }
    *(short8*)(Xb + (size_t)n * 512 + bb_ * 256 + c) = p;
}

// ---- bounds: bnd[r] = lower_bound(idx_rec, r), r in [0, N_REC]
__global__ void bounds_kernel(const int* __restrict__ idx_rec, int* __restrict__ bnd) {
    int r = blockIdx.x * 256 + threadIdx.x;
    if (r > N_REC) return;
    int lo = 0, hi = NEDGE;
    while (lo < hi) { int mid = (lo + hi) >> 1; if (idx_rec[mid] < r) lo = mid + 1; else hi = mid; }
    bnd[r] = lo;
}

// LDS tile indexing. XOR swizzle both sides (write & read use the same bijection).
// XT rows: 32 (= batch*16 + rl). HT rows: 16 (rl), batch halves at +4b shorts.
#define XTU(f, row) ((((f) * 32) + ((row) ^ ((f) & 7))) * 8)
#define HTU(f, rl)  ((((f) * 16) + ((rl) ^ ((f) & 7))) * 8)

// ==== fused16: 16 receivers/block, 512 threads = 8 waves, ~57 KB LDS -> 2 blocks/CU.
// phase 1 (DMA-chunked gather): per CHK=32 edges:
//   stage idx/EA -> issue 32 global_load_lds edge-row gathers (4/wave, per-lane global
//   src, slot-uniform LDS dest) -> H-MLP compute overlaps the DMA flight -> barrier
//   (vmcnt drain) -> consume rows from SBUF via ds_read_b128 into xacc.
//   Latency paid once per chunk, not once per edge; compiler cannot sink DMA loads.
// phase 2 (R8-verbatim, refcheck-passed): GEMM1 K=512 + gelu -> T; GEMM2 K=256 -> OUT.
// Rows: row = m (0..31); batch = m>>4; receiver rl = m&15. H shared across batches.
__global__ __launch_bounds__(512, 4)
void fused16(const int* __restrict__ idx_send, const int* __restrict__ bnd,
             const float* __restrict__ EA, const float* __restrict__ We1,
             const float* __restrict__ be1, const short* __restrict__ Xb,
             const short* __restrict__ BT1, const short* __restrict__ WT2,
             const float* __restrict__ cvec, const float* __restrict__ bl1,
             const float* __restrict__ bl2, float* __restrict__ OUT) {
    __shared__ __attribute__((aligned(16))) short SBUF[CHK * 512];  // 32 KB gathered rows [e][b*256+c]
    __shared__ __attribute__((aligned(16))) short XT[32 * 32 * 8];  // 16 KB; reused for T
    __shared__ __attribute__((aligned(16))) short HT[32 * 16 * 8];  //  8 KB
    __shared__ int   sb[RECV + 1];
    __shared__ int   s_idx[CHK];
    __shared__ __attribute__((aligned(16))) float s_ea[CHK * 4];

    int t = threadIdx.x;
    int r0 = blockIdx.x * RECV;
    if (t <= RECV) sb[t] = bnd[r0 + t];
    __syncthreads();
    int e0 = sb[0], eN = sb[RECV];

    int cg = t & 31;          // 8-col group
    int b  = (t >> 5) & 1;    // batch
    int rh = t >> 6;          // wave id: receivers rh*2, rh*2+1
    int lane = t & 63;
    int c8 = cg * 8;
    int hc = c8 + 4 * b;

    // ---------------- phase 1: DMA-chunked aggregate ----------------
    {
        floatx4 w0 = *(const floatx4*)(We1 + hc);
        floatx4 w1 = *(const floatx4*)(We1 + 256 + hc);
        floatx4 w2 = *(const floatx4*)(We1 + 512 + hc);
        floatx4 w3 = *(const floatx4*)(We1 + 768 + hc);
        floatx4 bb = *(const floatx4*)(be1 + hc);

        float xacc[2][8];
        float hacc[2][4];
#pragma unroll
        for (int r = 0; r < 2; ++r) {
#pragma unroll
            for (int c = 0; c < 8; ++c) xacc[r][c] = 0.f;
#pragma unroll
            for (int c = 0; c < 4; ++c) hacc[r][c] = 0.f;
        }

        for (int base = e0; base < eN; base += CHK) {
            int cnt = min(CHK, eN - base);
            __syncthreads();   // previous chunk fully consumed; SBUF/s_idx/s_ea free
            if (t < cnt) {
                s_idx[t] = idx_send[base + t];
                *(floatx4*)(s_ea + 4 * t) = *(const floatx4*)(EA + (size_t)(base + t) * 4);
            }
            __syncthreads();
            // issue gathers: 4 slots per wave (slot uniform per wave -> legal LDS dest)
#pragma unroll
            for (int k = 0; k < 4; ++k) {
                int slot = rh + 8 * k;
                if (slot < cnt) {
                    int s = s_idx[slot];   // wave-uniform
                    gload_lds16(Xb + (size_t)s * 512 + lane * 8,
                                SBUF + slot * 512 + lane * 8);
                }
            }
            // H-MLP for this chunk: depends only on s_ea -> overlaps the DMA flight
#pragma unroll
            for (int r = 0; r < 2; ++r) {
                int rl = rh * 2 + r;
                int es = max(sb[rl], base);
                int ee = min(sb[rl + 1], base + cnt);
                for (int e = es; e < ee; ++e) {
                    floatx4 a = *(const floatx4*)(s_ea + 4 * (e - base));
#pragma unroll
                    for (int j = 0; j < 4; ++j) {
                        float u = a[0] * w0[j] + a[1] * w1[j] + a[2] * w2[j]
                                + a[3] * w3[j] + bb[j];
                        hacc[r][j] += gelu_tanh(u);
                    }
                }
            }
            __syncthreads();   // drains vmcnt(0): SBUF rows are ready
            // X-consume from LDS (short-latency ds_read, pipelined by compiler)
#pragma unroll
            for (int r = 0; r < 2; ++r) {
                int rl = rh * 2 + r;
                int es = max(sb[rl], base);
                int ee = min(sb[rl + 1], base + cnt);
                for (int e = es; e < ee; ++e) {
                    int li = e - base;
                    uintx4 xv = *(const uintx4*)(SBUF + li * 512 + b * 256 + c8);
#pragma unroll
                    for (int dw = 0; dw < 4; ++dw) {
                        xacc[r][2 * dw]     += __builtin_bit_cast(float, xv[dw] << 16);
                        xacc[r][2 * dw + 1] += __builtin_bit_cast(float, xv[dw] & 0xffff0000u);
                    }
                }
            }
        }
        // flush fragment-major tiles
#pragma unroll
        for (int r = 0; r < 2; ++r) {
            int rl = rh * 2 + r;
            short8 xp;
#pragma unroll
            for (int c = 0; c < 8; ++c) xp[c] = f2bs(xacc[r][c]);
            *(short8*)(XT + XTU(cg, b * RECV + rl)) = xp;
            shortx4 hp;
#pragma unroll
            for (int c = 0; c < 4; ++c) hp[c] = f2bs(hacc[r][c]);
            *(shortx4*)(HT + HTU(cg, rl) + 4 * b) = hp;
        }
    }
    __syncthreads();

    // ---------------- GEMM1 (K=512) ----------------
    int w = t >> 6;
    int m = lane & 31, q = lane >> 5;
    int wcol = w * 32;
    floatx16 acc;
#pragma unroll
    for (int j = 0; j < 16; ++j) acc[j] = 0.f;

    const short* Bp1 = BT1 + (size_t)(wcol + m) * 512 + q * 8;
#pragma unroll
    for (int ci = 0; ci < 8; ++ci) {
#pragma unroll
        for (int kk = 0; kk < 4; ++kk) {
            short8 bv = *(const short8*)(Bp1 + ci * 64 + kk * 16);
            int f = ci * 8 + 2 * kk + q;
            short8 a0;
            if (ci < 4) {
                a0 = *(const short8*)(XT + XTU(f, m));
            } else {
                a0 = *(const short8*)(HT + HTU(f - 32, m & 15));   // H shared across batches
            }
            acc = __builtin_amdgcn_mfma_f32_32x32x16_bf16(bv, a0, acc, 0, 0, 0);
        }
    }
    __syncthreads();   // all waves done reading XT/HT

    // ---- epilogue1: gelu(acc + cnt*cvec + bl1) -> T (into XT, fragment-major) ----
    {
        int rl = m & 15;
        float cntv = (float)(sb[rl + 1] - sb[rl]);
#pragma unroll
        for (int qd = 0; qd < 4; ++qd) {
            int c0 = wcol + qd * 8 + q * 4;
            floatx4 cv  = *(const floatx4*)(cvec + c0);
            floatx4 b1v = *(const floatx4*)(bl1 + c0);
            shortx4 pk;
#pragma unroll
            for (int j = 0; j < 4; ++j)
                pk[j] = f2bs(gelu_tanh(acc[qd * 4 + j] + cntv * cv[j] + b1v[j]));
            *(shortx4*)(XT + XTU(w * 4 + qd, m) + q * 4) = pk;
        }
#pragma unroll
        for (int j = 0; j < 16; ++j) acc[j] = 0.f;
    }
    __syncthreads();

    // ---------------- GEMM2 (K=256): T @ WT2^T ----------------
    const short* Bp2 = WT2 + (size_t)(wcol + m) * 256 + q * 8;
#pragma unroll
    for (int ci = 0; ci < 4; ++ci) {
#pragma unroll
        for (int kk = 0; kk < 4; ++kk) {
            short8 bv = *(const short8*)(Bp2 + ci * 64 + kk * 16);
            int f2 = ci * 8 + 2 * kk + q;
            short8 a0 = *(const short8*)(XT + XTU(f2, m));
            acc = __builtin_amdgcn_mfma_f32_32x32x16_bf16(bv, a0, acc, 0, 0, 0);
        }
    }

    // ---- epilogue2: + bl2 -> OUT (batch = m>>4, receiver = r0 + (m&15)) ----
    {
        int bat = m >> 4;
        int rl = m & 15;
        size_t obase = ((size_t)bat * N_REC + r0 + rl) * 256;
#pragma unroll
        for (int qd = 0; qd < 4; ++qd) {
            int c0 = wcol + qd * 8 + q * 4;
            floatx4 bv = *(const floatx4*)(bl2 + c0);
            floatx4 o;
#pragma unroll
            for (int j = 0; j < 4; ++j)
                o[j] = acc[qd * 4 + j] + bv[j];
            *(floatx4*)(OUT + obase + c0) = o;
        }
    }
}

extern "C" void kernel_launch(void* const* d_in, const int* in_sizes, int n_in,
                              void* d_out, int out_size, void* d_ws, size_t ws_size,
                              hipStream_t stream) {
    const float* x        = (const float*)d_in[0];
    const float* ea       = (const float*)d_in[1];
    const int*   idx_send = (const int*)d_in[2];
    const int*   idx_rec  = (const int*)d_in[3];
    const float* We1      = (const float*)d_in[4];
    const float* be1      = (const float*)d_in[5];
    const float* We2      = (const float*)d_in[6];
    const float* be2      = (const float*)d_in[7];
    const float* Wl1      = (const float*)d_in[8];
    const float* bl1      = (const float*)d_in[9];
    const float* Wl2      = (const float*)d_in[10];
    const float* bl2      = (const float*)d_in[11];
    float* out = (float*)d_out;
    char*  ws  = (char*)d_ws;

    short* BT1  = (short*)(ws + 0);           // 262144 B
    short* WT2  = (short*)(ws + 262144);      // 131072 B
    float* cvec = (float*)(ws + 393216);      // 1024 B
    int*   bnd  = (int*)  (ws + 397312);      // 196612 B
    short* Xb   = (short*)(ws + 1048576);     // 12.58 MB

    prep_kernel<<<257, 256, 0, stream>>>(We2, be2, Wl1, Wl2, BT1, WT2, cvec);
    xcast_kernel<<<(2 * N_SEND * 256) / (256 * 8), 256, 0, stream>>>(x, Xb);
    bounds_kernel<<<(N_REC + 1 + 255) / 256, 256, 0, stream>>>(idx_rec, bnd);
    fused16<<<N_REC / RECV, 512, 0, stream>>>(idx_send, bnd, ea, We1, be1, Xb,
                                              BT1, WT2, cvec, bl1, bl2, out);
}

// Round 11
// 332.858 us; speedup vs baseline: 1.1122x; 1.1122x over previous
//
#include <hip/hip_runtime.h>
#include <hip/hip_bf16.h>

#define N_SEND 12288
#define N_REC  49152
#define NEDGE  196608
#define RECV   16          // receivers per block; M = 32 rows = 1 row-tile

typedef __attribute__((ext_vector_type(8)))  short short8;
typedef __attribute__((ext_vector_type(4)))  short shortx4;
typedef __attribute__((ext_vector_type(4)))  float floatx4;
typedef __attribute__((ext_vector_type(16))) float floatx16;
typedef __attribute__((ext_vector_type(4)))  unsigned int uintx4;

__device__ inline short f2bs(float f) {
    __hip_bfloat16 h = __float2bfloat16(f);
    return *reinterpret_cast<short*>(&h);
}
// jax.nn.gelu default approximate=True (tanh form)
__device__ inline float gelu_tanh(float x) {
    const float k0 = 0.7978845608028654f;
    float u = k0 * (x + 0.044715f * x * x * x);
    float e = __expf(2.0f * u);
    float t = 1.0f - 2.0f / (e + 1.0f);
    return 0.5f * x * (1.0f + t);
}

// ---- prep: BT1[n][0:256]=Wl1lo^T, BT1[n][256:512]=(We2@Wl1hi)^T, WT2=Wl2^T, cvec=be2@Wl1hi
__global__ void prep_kernel(const float* __restrict__ We2, const float* __restrict__ be2,
                            const float* __restrict__ Wl1, const float* __restrict__ Wl2,
                            short* __restrict__ BT1, short* __restrict__ WT2,
                            float* __restrict__ cvec) {
    int i = blockIdx.x;
    int n = threadIdx.x;
    if (i < 256) {
        float acc = 0.f;
        for (int j = 0; j < 256; ++j)
            acc += We2[i * 256 + j] * Wl1[(256 + j) * 256 + n];
        BT1[n * 512 + i]       = f2bs(Wl1[i * 256 + n]);   // k<256: Wl1lo
        BT1[n * 512 + 256 + i] = f2bs(acc);                // k>=256: M = We2@Wl1hi
        WT2[n * 256 + i]       = f2bs(Wl2[i * 256 + n]);
    } else {
        float acc = 0.f;
        for (int j = 0; j < 256; ++j)
            acc += be2[j] * Wl1[(256 + j) * 256 + n];
        cvec[n] = acc;
    }
}

// ---- xcast: Xb = bf16(X), interleaved [send][batch][256] (edge's 1KB contiguous)
__global__ void xcast_kernel(const float* __restrict__ X, short* __restrict__ Xb) {
    int i = (blockIdx.x * 256 + threadIdx.x) * 8;
    int row = i >> 8;                 // b*N_SEND + n
    int c   = i & 255;
    int bb_ = (row >= N_SEND) ? 1 : 0;
    int n   = row - bb_ * N_SEND;
    floatx4 v0 = *(const floatx4*)(X + i);
    floatx4 v1 = *(const floatx4*)(X + i + 4);
    short8 p;
#pragma unroll
    for (int j = 0; j < 4; ++j) { p[j] = f2bs(v0[j]); p[j + 4] = f2bs(v1[j]); }
    *(short8*)(Xb + (size_t)n * 512 + bb_ * 256 + c) = p;
}

// ---- bounds: bnd[r] = lower_bound(idx_rec, r), r in [0, N_REC]
__global__ void bounds_kernel(const int* __restrict__ idx_rec, int* __restrict__ bnd) {
    int r = blockIdx.x * 256 + threadIdx.x;
    if (r > N_REC) return;
    int lo = 0, hi = NEDGE;
    while (lo < hi) { int mid = (lo + hi) >> 1; if (idx_rec[mid] < r) lo = mid + 1; else hi = mid; }
    bnd[r] = lo;
}

// LDS tile indexing. XOR swizzle both sides (write & read use the same bijection).
// XT rows: 32 (= batch*16 + rl). HT rows: 16 (rl), batch halves at +4b shorts.
#define XTU(f, row) ((((f) * 32) + ((row) ^ ((f) & 7))) * 8)
#define HTU(f, rl)  ((((f) * 16) + ((rl) ^ ((f) & 7))) * 8)

// ==== fused16b: 16 receivers/block, 256 threads = 4 waves, ~24.3 KB LDS.
// __launch_bounds__(256, 5): 5 blocks/CU = 20 waves/CU, VGPR budget ~102.
// The extra registers (vs R4/R8's 64) let the compiler keep a 1-deep gather
// prefetch in flight: xvN issued BEFORE xvC is consumed (explicit in source).
// phase 1: per-receiver serial aggregation (4 receivers/wave), 1-deep idx/EA
//          prefetch + 1-deep gather prefetch, fragments into swizzled LDS.
// phase 2: GEMM1 K=512 ([X|H] @ BT1^T) + gelu -> T in LDS; GEMM2 K=256 -> OUT.
//          4 waves x 2 column-tiles (acc[2]); layouts identical to R8 (passed).
// Rows: row = m (0..31); batch = m>>4; receiver rl = m&15. H shared across batches.
__global__ __launch_bounds__(256, 5)
void fused16b(const int* __restrict__ idx_send, const int* __restrict__ bnd,
              const float* __restrict__ EA, const float* __restrict__ We1,
              const float* __restrict__ be1, const short* __restrict__ Xb,
              const short* __restrict__ BT1, const short* __restrict__ WT2,
              const float* __restrict__ cvec, const float* __restrict__ bl1,
              const float* __restrict__ bl2, float* __restrict__ OUT) {
    __shared__ __attribute__((aligned(16))) short XT[32 * 32 * 8];  // 16 KB; reused for T
    __shared__ __attribute__((aligned(16))) short HT[32 * 16 * 8];  //  8 KB
    __shared__ int sb[RECV + 1];

    int t = threadIdx.x;
    int r0 = blockIdx.x * RECV;
    if (t <= RECV) sb[t] = bnd[r0 + t];
    __syncthreads();

    int lane = t & 63;
    int w = t >> 6;           // wave id 0..3

    // ---------------- phase 1: aggregate ----------------
    {
        int cg = lane & 31;       // 8-col group
        int b  = lane >> 5;       // batch
        int c8 = cg * 8;
        int hc = c8 + 4 * b;

        floatx4 w0 = *(const floatx4*)(We1 + hc);
        floatx4 w1 = *(const floatx4*)(We1 + 256 + hc);
        floatx4 w2 = *(const floatx4*)(We1 + 512 + hc);
        floatx4 w3 = *(const floatx4*)(We1 + 768 + hc);
        floatx4 bb = *(const floatx4*)(be1 + hc);
        const short* xb_t = Xb + b * 256 + c8;   // interleaved: row s at s*512

#pragma unroll
        for (int r = 0; r < 4; ++r) {
            int rl = w * 4 + r;   // wave w owns receivers w*4 .. w*4+3
            int es = __builtin_amdgcn_readfirstlane(sb[rl]);
            int ee = __builtin_amdgcn_readfirstlane(sb[rl + 1]);

            float xacc[8];
            float hacc[4];
#pragma unroll
            for (int c = 0; c < 8; ++c) xacc[c] = 0.f;
#pragma unroll
            for (int c = 0; c < 4; ++c) hacc[c] = 0.f;

            if (es < ee) {
                // pipeline head: current edge's idx/EA/gather all in flight
                int     sC  = idx_send[es];
                floatx4 aC  = *(const floatx4*)(EA + (size_t)es * 4);
                uintx4  xvC = *(const uintx4*)(xb_t + (size_t)sC * 512);
                for (int e = es; e < ee; ++e) {
                    int ep = (e + 1 < ee) ? e + 1 : e;
                    int     sN  = idx_send[ep];
                    floatx4 aN  = *(const floatx4*)(EA + (size_t)ep * 4);
                    uintx4  xvN = *(const uintx4*)(xb_t + (size_t)sN * 512); // issued before consume
#pragma unroll
                    for (int dw = 0; dw < 4; ++dw) {
                        xacc[2 * dw]     += __builtin_bit_cast(float, xvC[dw] << 16);
                        xacc[2 * dw + 1] += __builtin_bit_cast(float, xvC[dw] & 0xffff0000u);
                    }
#pragma unroll
                    for (int j = 0; j < 4; ++j) {
                        float u = aC[0] * w0[j] + aC[1] * w1[j] + aC[2] * w2[j]
                                + aC[3] * w3[j] + bb[j];
                        hacc[j] += gelu_tanh(u);
                    }
                    sC = sN; aC = aN; xvC = xvN;
                }
            }
            short8 xp;
#pragma unroll
            for (int c = 0; c < 8; ++c) xp[c] = f2bs(xacc[c]);
            *(short8*)(XT + XTU(cg, b * RECV + rl)) = xp;
            shortx4 hp;
#pragma unroll
            for (int c = 0; c < 4; ++c) hp[c] = f2bs(hacc[c]);
            *(shortx4*)(HT + HTU(cg, rl) + 4 * b) = hp;
        }
    }
    __syncthreads();

    // ---------------- GEMM1 (K=512): 4 waves x 2 col-tiles ----------------
    int m = lane & 31, q = lane >> 5;
    floatx16 acc0, acc1;    // col-tiles ct=0,1 (cols w*64 .. w*64+63)
#pragma unroll
    for (int j = 0; j < 16; ++j) { acc0[j] = 0.f; acc1[j] = 0.f; }

    const short* Bp1a = BT1 + (size_t)(w * 64 + m) * 512 + q * 8;
    const short* Bp1b = BT1 + (size_t)(w * 64 + 32 + m) * 512 + q * 8;
#pragma unroll
    for (int ci = 0; ci < 8; ++ci) {
#pragma unroll
        for (int kk = 0; kk < 4; ++kk) {
            short8 bva = *(const short8*)(Bp1a + ci * 64 + kk * 16);
            short8 bvb = *(const short8*)(Bp1b + ci * 64 + kk * 16);
            int f = ci * 8 + 2 * kk + q;
            short8 a0;
            if (ci < 4) {
                a0 = *(const short8*)(XT + XTU(f, m));
            } else {
                a0 = *(const short8*)(HT + HTU(f - 32, m & 15));   // H shared across batches
            }
            acc0 = __builtin_amdgcn_mfma_f32_32x32x16_bf16(bva, a0, acc0, 0, 0, 0);
            acc1 = __builtin_amdgcn_mfma_f32_32x32x16_bf16(bvb, a0, acc1, 0, 0, 0);
        }
    }
    __syncthreads();   // all waves done reading XT/HT

    // ---- epilogue1: gelu(acc + cnt*cvec + bl1) -> T (into XT, fragment-major) ----
    {
        int rl = m & 15;
        float cntv = (float)(sb[rl + 1] - sb[rl]);
#pragma unroll
        for (int ct = 0; ct < 2; ++ct) {
            const floatx16& ac = ct ? acc1 : acc0;
#pragma unroll
            for (int qd = 0; qd < 4; ++qd) {
                int c0 = w * 64 + ct * 32 + qd * 8 + q * 4;
                floatx4 cv  = *(const floatx4*)(cvec + c0);
                floatx4 b1v = *(const floatx4*)(bl1 + c0);
                shortx4 pk;
#pragma unroll
                for (int j = 0; j < 4; ++j)
                    pk[j] = f2bs(gelu_tanh(ac[qd * 4 + j] + cntv * cv[j] + b1v[j]));
                *(shortx4*)(XT + XTU(w * 8 + ct * 4 + qd, m) + q * 4) = pk;
            }
        }
#pragma unroll
        for (int j = 0; j < 16; ++j) { acc0[j] = 0.f; acc1[j] = 0.f; }
    }
    __syncthreads();

    // ---------------- GEMM2 (K=256): T @ WT2^T ----------------
    const short* Bp2a = WT2 + (size_t)(w * 64 + m) * 256 + q * 8;
    const short* Bp2b = WT2 + (size_t)(w * 64 + 32 + m) * 256 + q * 8;
#pragma unroll
    for (int ci = 0; ci < 4; ++ci) {
#pragma unroll
        for (int kk = 0; kk < 4; ++kk) {
            short8 bva = *(const short8*)(Bp2a + ci * 64 + kk * 16);
            short8 bvb = *(const short8*)(Bp2b + ci * 64 + kk * 16);
            int f2 = ci * 8 + 2 * kk + q;
            short8 a0 = *(const short8*)(XT + XTU(f2, m));
            acc0 = __builtin_amdgcn_mfma_f32_32x32x16_bf16(bva, a0, acc0, 0, 0, 0);
            acc1 = __builtin_amdgcn_mfma_f32_32x32x16_bf16(bvb, a0, acc1, 0, 0, 0);
        }
    }

    // ---- epilogue2: + bl2 -> OUT (batch = m>>4, receiver = r0 + (m&15)) ----
    {
        int bat = m >> 4;
        int rl = m & 15;
        size_t obase = ((size_t)bat * N_REC + r0 + rl) * 256;
#pragma unroll
        for (int ct = 0; ct < 2; ++ct) {
            const floatx16& ac = ct ? acc1 : acc0;
#pragma unroll
            for (int qd = 0; qd < 4; ++qd) {
                int c0 = w * 64 + ct * 32 + qd * 8 + q * 4;
                floatx4 bv = *(const floatx4*)(bl2 + c0);
                floatx4 o;
#pragma unroll
                for (int j = 0; j < 4; ++j)
                    o[j] = ac[qd * 4 + j] + bv[j];
                *(floatx4*)(OUT + obase + c0) = o;
            }
        }
    }
}

extern "C" void kernel_launch(void* const* d_in, const int* in_sizes, int n_in,
                              void* d_out, int out_size, void* d_ws, size_t ws_size,
                              hipStream_t stream) {
    const float* x        = (const float*)d_in[0];
    const float* ea       = (const float*)d_in[1];
    const int*   idx_send = (const int*)d_in[2];
    const int*   idx_rec  = (const int*)d_in[3];
    const float* We1      = (const float*)d_in[4];
    const float* be1      = (const float*)d_in[5];
    const float* We2      = (const float*)d_in[6];
    const float* be2      = (const float*)d_in[7];
    const float* Wl1      = (const float*)d_in[8];
    const float* bl1      = (const float*)d_in[9];
    const float* Wl2      = (const float*)d_in[10];
    const float* bl2      = (const float*)d_in[11];
    float* out = (float*)d_out;
    char*  ws  = (char*)d_ws;

    short* BT1  = (short*)(ws + 0);           // 262144 B
    short* WT2  = (short*)(ws + 262144);      // 131072 B
    float* cvec = (float*)(ws + 393216);      // 1024 B
    int*   bnd  = (int*)  (ws + 397312);      // 196612 B
    short* Xb   = (short*)(ws + 1048576);     // 12.58 MB

    prep_kernel<<<257, 256, 0, stream>>>(We2, be2, Wl1, Wl2, BT1, WT2, cvec);
    xcast_kernel<<<(2 * N_SEND * 256) / (256 * 8), 256, 0, stream>>>(x, Xb);
    bounds_kernel<<<(N_REC + 1 + 255) / 256, 256, 0, stream>>>(idx_rec, bnd);
    fused16b<<<N_REC / RECV, 256, 0, stream>>>(idx_send, bnd, ea, We1, be1, Xb,
                                               BT1, WT2, cvec, bl1, bl2, out);
}

// Round 12
// 271.674 us; speedup vs baseline: 1.3626x; 1.2252x over previous
//
#include <hip/hip_runtime.h>
#include <hip/hip_bf16.h>

#define N_SEND 12288
#define N_REC  49152
#define NEDGE  196608
#define RECV   48          // receivers per block; M = 96 rows = 3 row-tiles

typedef __attribute__((ext_vector_type(8)))  short short8;
typedef __attribute__((ext_vector_type(4)))  short shortx4;
typedef __attribute__((ext_vector_type(4)))  float floatx4;
typedef __attribute__((ext_vector_type(16))) float floatx16;
typedef __attribute__((ext_vector_type(4)))  unsigned int uintx4;

__device__ inline short f2bs(float f) {
    __hip_bfloat16 h = __float2bfloat16(f);
    return *reinterpret_cast<short*>(&h);
}
// jax.nn.gelu default approximate=True (tanh form)
__device__ inline float gelu_tanh(float x) {
    const float k0 = 0.7978845608028654f;
    float u = k0 * (x + 0.044715f * x * x * x);
    float e = __expf(2.0f * u);
    float t = 1.0f - 2.0f / (e + 1.0f);
    return 0.5f * x * (1.0f + t);
}

// ---- prep: BT1[n][0:256]=Wl1lo^T, BT1[n][256:512]=(We2@Wl1hi)^T, WT2=Wl2^T, cvec=be2@Wl1hi
__global__ void prep_kernel(const float* __restrict__ We2, const float* __restrict__ be2,
                            const float* __restrict__ Wl1, const float* __restrict__ Wl2,
                            short* __restrict__ BT1, short* __restrict__ WT2,
                            float* __restrict__ cvec) {
    int i = blockIdx.x;
    int n = threadIdx.x;
    if (i < 256) {
        float acc = 0.f;
        for (int j = 0; j < 256; ++j)
            acc += We2[i * 256 + j] * Wl1[(256 + j) * 256 + n];
        BT1[n * 512 + i]       = f2bs(Wl1[i * 256 + n]);   // k<256: Wl1lo
        BT1[n * 512 + 256 + i] = f2bs(acc);                // k>=256: M = We2@Wl1hi
        WT2[n * 256 + i]       = f2bs(Wl2[i * 256 + n]);
    } else {
        float acc = 0.f;
        for (int j = 0; j < 256; ++j)
            acc += be2[j] * Wl1[(256 + j) * 256 + n];
        cvec[n] = acc;
    }
}

// ---- xcast: Xb = bf16(X), interleaved [send][batch][256] (edge's 1KB contiguous)
__global__ void xcast_kernel(const float* __restrict__ X, short* __restrict__ Xb) {
    int i = (blockIdx.x * 256 + threadIdx.x) * 8;
    int row = i >> 8;                 // b*N_SEND + n
    int c   = i & 255;
    int bb_ = (row >= N_SEND) ? 1 : 0;
    int n   = row - bb_ * N_SEND;
    floatx4 v0 = *(const floatx4*)(X + i);
    floatx4 v1 = *(const floatx4*)(X + i + 4);
    short8 p;
#pragma unroll
    for (int j = 0; j < 4; ++j) { p[j] = f2bs(v0[j]); p[j + 4] = f2bs(v1[j]); }
    *(short8*)(Xb + (size_t)n * 512 + bb_ * 256 + c) = p;
}

// ---- bounds: bnd[r] = lower_bound(idx_rec, r), r in [0, N_REC]
__global__ void bounds_kernel(const int* __restrict__ idx_rec, int* __restrict__ bnd) {
    int r = blockIdx.x * 256 + threadIdx.x;
    if (r > N_REC) return;
    int lo = 0, hi = NEDGE;
    while (lo < hi) { int mid = (lo + hi) >> 1; if (idx_rec[mid] < r) lo = mid + 1; else hi = mid; }
    bnd[r] = lo;
}

// LDS tile indexing. XOR swizzle both sides (write & read use the same bijection).
#define XTU(f, row) ((((f) * 96) + ((row) ^ ((f) & 7))) * 8)
#define HTU(f, rl)  ((((f) * 48) + ((rl) ^ ((f) & 7))) * 8)

// ==== fused48 (R4 champion + coalesced-OUT epilogue): 48 receivers/block, 512 threads,
// ~72.4 KB LDS -> 2 blocks/CU.
// phase 1: per-receiver serial aggregation, 1-deep idx/EA prefetch (R4-verbatim).
// phase 2: GEMM1 K=512 + gelu -> T; GEMM2 K=256; NEW epilogue2: stage output rows in
//          LDS (XT reused as float[48][256], col-XOR-swizzled), then each wave writes
//          one FULL 1KB contiguous row per store instruction (64 lanes x 16B).
__global__ __launch_bounds__(512, 4)
void fused48(const int* __restrict__ idx_send, const int* __restrict__ bnd,
             const float* __restrict__ EA, const float* __restrict__ We1,
             const float* __restrict__ be1, const short* __restrict__ Xb,
             const short* __restrict__ BT1, const short* __restrict__ WT2,
             const float* __restrict__ cvec, const float* __restrict__ bl1,
             const float* __restrict__ bl2, float* __restrict__ OUT) {
    __shared__ __attribute__((aligned(16))) short XT[32 * 96 * 8];  // 48 KB; reused for T, then f32 out-stage
    __shared__ __attribute__((aligned(16))) short HT[32 * 48 * 8];  // 24 KB
    __shared__ int sb[RECV + 1];

    int t = threadIdx.x;
    int r0 = blockIdx.x * RECV;
    if (t <= RECV) sb[t] = bnd[r0 + t];
    __syncthreads();

    // ---------------- phase 1: aggregate (R4-verbatim) ----------------
    {
        int cg = t & 31;          // 8-col group
        int b  = (t >> 5) & 1;    // batch
        int rh = t >> 6;          // wave id: receivers rh*6 .. rh*6+5
        int c8 = cg * 8;
        int hc = c8 + 4 * b;

        floatx4 w0 = *(const floatx4*)(We1 + hc);
        floatx4 w1 = *(const floatx4*)(We1 + 256 + hc);
        floatx4 w2 = *(const floatx4*)(We1 + 512 + hc);
        floatx4 w3 = *(const floatx4*)(We1 + 768 + hc);
        floatx4 bb = *(const floatx4*)(be1 + hc);
        const short* xb_t = Xb + b * 256 + c8;   // interleaved: row s at s*512

#pragma unroll
        for (int r = 0; r < 6; ++r) {
            int rl = rh * 6 + r;
            int es = __builtin_amdgcn_readfirstlane(sb[rl]);
            int ee = __builtin_amdgcn_readfirstlane(sb[rl + 1]);

            float xacc[8];
            float hacc[4];
#pragma unroll
            for (int c = 0; c < 8; ++c) xacc[c] = 0.f;
#pragma unroll
            for (int c = 0; c < 4; ++c) hacc[c] = 0.f;

            int s = 0; floatx4 a = {0.f, 0.f, 0.f, 0.f};
            if (es < ee) { s = idx_send[es]; a = *(const floatx4*)(EA + (size_t)es * 4); }
            for (int e = es; e < ee; ++e) {
                int cs = s; floatx4 ca = a;
                int ep = (e + 1 < ee) ? e + 1 : e;          // branchless 1-deep prefetch
                s = idx_send[ep];
                a = *(const floatx4*)(EA + (size_t)ep * 4);
                uintx4 xv = *(const uintx4*)(xb_t + (size_t)cs * 512);
#pragma unroll
                for (int dw = 0; dw < 4; ++dw) {
                    xacc[2 * dw]     += __builtin_bit_cast(float, xv[dw] << 16);
                    xacc[2 * dw + 1] += __builtin_bit_cast(float, xv[dw] & 0xffff0000u);
                }
#pragma unroll
                for (int j = 0; j < 4; ++j) {
                    float u = ca[0] * w0[j] + ca[1] * w1[j] + ca[2] * w2[j] + ca[3] * w3[j] + bb[j];
                    hacc[j] += gelu_tanh(u);
                }
            }
            short8 xp;
#pragma unroll
            for (int c = 0; c < 8; ++c) xp[c] = f2bs(xacc[c]);
            *(short8*)(XT + XTU(cg, b * RECV + rl)) = xp;
            shortx4 hp;
#pragma unroll
            for (int c = 0; c < 4; ++c) hp[c] = f2bs(hacc[c]);
            *(shortx4*)(HT + HTU(cg, rl) + 4 * b) = hp;
        }
    }
    __syncthreads();

    // ---------------- GEMM1 (K=512) ----------------
    int w = t >> 6, lane = t & 63;
    int m = lane & 31, q = lane >> 5;
    int wcol = w * 32;
    floatx16 acc[3];
#pragma unroll
    for (int i = 0; i < 3; ++i)
#pragma unroll
        for (int j = 0; j < 16; ++j) acc[i][j] = 0.f;

    const short* Bp1 = BT1 + (size_t)(wcol + m) * 512 + q * 8;
#pragma unroll
    for (int ci = 0; ci < 8; ++ci) {
#pragma unroll
        for (int kk = 0; kk < 4; ++kk) {
            short8 bv = *(const short8*)(Bp1 + ci * 64 + kk * 16);
            int f = ci * 8 + 2 * kk + q;
            short8 a0, a1, a2;
            if (ci < 4) {
                a0 = *(const short8*)(XT + XTU(f, m));
                a1 = *(const short8*)(XT + XTU(f, 32 + m));
                a2 = *(const short8*)(XT + XTU(f, 64 + m));
            } else {
                int fh = f - 32;
                a0 = *(const short8*)(HT + HTU(fh, m));                   // rows 0..31  -> rl=m
                int rl1 = (m < 16) ? 32 + m : m - 16;                     // rows 32..63
                a1 = *(const short8*)(HT + HTU(fh, rl1));
                a2 = *(const short8*)(HT + HTU(fh, 16 + m));              // rows 64..95 -> rl=16+m
            }
            acc[0] = __builtin_amdgcn_mfma_f32_32x32x16_bf16(bv, a0, acc[0], 0, 0, 0);
            acc[1] = __builtin_amdgcn_mfma_f32_32x32x16_bf16(bv, a1, acc[1], 0, 0, 0);
            acc[2] = __builtin_amdgcn_mfma_f32_32x32x16_bf16(bv, a2, acc[2], 0, 0, 0);
        }
    }
    __syncthreads();   // all waves done reading XT/HT

    // ---- epilogue1: gelu(acc + cnt*cvec + bl1) -> T (into XT, fragment-major) ----
#pragma unroll
    for (int qd = 0; qd < 4; ++qd) {
        int c0 = wcol + qd * 8 + q * 4;
        floatx4 cv  = *(const floatx4*)(cvec + c0);
        floatx4 b1v = *(const floatx4*)(bl1 + c0);
#pragma unroll
        for (int rt = 0; rt < 3; ++rt) {
            int r = rt * 32 + m;
            int bat = (r >= RECV) ? 1 : 0;
            int rl = r - RECV * bat;
            float cntv = (float)(sb[rl + 1] - sb[rl]);
            shortx4 pk;
#pragma unroll
            for (int j = 0; j < 4; ++j)
                pk[j] = f2bs(gelu_tanh(acc[rt][qd * 4 + j] + cntv * cv[j] + b1v[j]));
            *(shortx4*)(XT + XTU(w * 4 + qd, r) + q * 4) = pk;
        }
    }
#pragma unroll
    for (int i = 0; i < 3; ++i)
#pragma unroll
        for (int j = 0; j < 16; ++j) acc[i][j] = 0.f;
    __syncthreads();

    // ---------------- GEMM2 (K=256): T @ WT2^T ----------------
    const short* Bp2 = WT2 + (size_t)(wcol + m) * 256 + q * 8;
#pragma unroll
    for (int ci = 0; ci < 4; ++ci) {
#pragma unroll
        for (int kk = 0; kk < 4; ++kk) {
            short8 bv = *(const short8*)(Bp2 + ci * 64 + kk * 16);
            int f2 = ci * 8 + 2 * kk + q;
            short8 a0 = *(const short8*)(XT + XTU(f2, m));
            short8 a1 = *(const short8*)(XT + XTU(f2, 32 + m));
            short8 a2 = *(const short8*)(XT + XTU(f2, 64 + m));
            acc[0] = __builtin_amdgcn_mfma_f32_32x32x16_bf16(bv, a0, acc[0], 0, 0, 0);
            acc[1] = __builtin_amdgcn_mfma_f32_32x32x16_bf16(bv, a1, acc[1], 0, 0, 0);
            acc[2] = __builtin_amdgcn_mfma_f32_32x32x16_bf16(bv, a2, acc[2], 0, 0, 0);
        }
    }
    __syncthreads();   // GEMM2's XT reads complete before reuse as f32 stage

    // ---- epilogue2 (NEW): + bl2 -> LDS stage -> coalesced 1KB-row writes ----
    // XT reused as float[48][256] (48 KB exact). Two passes; pass p == batch p
    // (rows r=rt*32+m in [48p,48p+48), LDS row = r-48p = receiver rl).
    {
        float* XF = (float*)XT;
#pragma unroll
        for (int p = 0; p < 2; ++p) {
            // stage this pass's rows (col XOR-swizzle breaks bank aliasing)
#pragma unroll
            for (int rt = 0; rt < 3; ++rt) {
                int r = rt * 32 + m;
                if (r >= 48 * p && r < 48 * p + 48) {
                    int row = r - 48 * p;
                    int sw = (row & 7) * 4;
#pragma unroll
                    for (int qd = 0; qd < 4; ++qd) {
                        int c0 = wcol + qd * 8 + q * 4;
                        floatx4 bv = *(const floatx4*)(bl2 + c0);
                        floatx4 o;
#pragma unroll
                        for (int j = 0; j < 4; ++j)
                            o[j] = acc[rt][qd * 4 + j] + bv[j];
                        *(floatx4*)(XF + row * 256 + (c0 ^ sw)) = o;
                    }
                }
            }
            __syncthreads();
            // coalesced write: 48 rows x 64 chunks; each wave = one full 1KB row
#pragma unroll
            for (int k = 0; k < 6; ++k) {
                int cid = t + k * 512;
                int row = cid >> 6;          // 0..47 (wave-uniform)
                int cc  = (cid & 63) * 4;    // float col of 16B chunk
                int sw  = (row & 7) * 4;
                floatx4 v = *(const floatx4*)(XF + row * 256 + (cc ^ sw));
                *(floatx4*)(OUT + ((size_t)p * N_REC + r0 + row) * 256 + cc) = v;
            }
            if (p == 0) __syncthreads();   // LDS reads done before pass-1 restage
        }
    }
}

extern "C" void kernel_launch(void* const* d_in, const int* in_sizes, int n_in,
                              void* d_out, int out_size, void* d_ws, size_t ws_size,
                              hipStream_t stream) {
    const float* x        = (const float*)d_in[0];
    const float* ea       = (const float*)d_in[1];
    const int*   idx_send = (const int*)d_in[2];
    const int*   idx_rec  = (const int*)d_in[3];
    const float* We1      = (const float*)d_in[4];
    const float* be1      = (const float*)d_in[5];
    const float* We2      = (const float*)d_in[6];
    const float* be2      = (const float*)d_in[7];
    const float* Wl1      = (const float*)d_in[8];
    const float* bl1      = (const float*)d_in[9];
    const float* Wl2      = (const float*)d_in[10];
    const float* bl2      = (const float*)d_in[11];
    float* out = (float*)d_out;
    char*  ws  = (char*)d_ws;

    short* BT1  = (short*)(ws + 0);           // 262144 B
    short* WT2  = (short*)(ws + 262144);      // 131072 B
    float* cvec = (float*)(ws + 393216);      // 1024 B
    int*   bnd  = (int*)  (ws + 397312);      // 196612 B
    short* Xb   = (short*)(ws + 1048576);     // 12.58 MB

    prep_kernel<<<257, 256, 0, stream>>>(We2, be2, Wl1, Wl2, BT1, WT2, cvec);
    xcast_kernel<<<(2 * N_SEND * 256) / (256 * 8), 256, 0, stream>>>(x, Xb);
    bounds_kernel<<<(N_REC + 1 + 255) / 256, 256, 0, stream>>>(idx_rec, bnd);
    fused48<<<N_REC / RECV, 512, 0, stream>>>(idx_send, bnd, ea, We1, be1, Xb,
                                              BT1, WT2, cvec, bl1, bl2, out);
}